// Round 6
// baseline (5312.774 us; speedup 1.0000x reference)
//
#include <hip/hip_runtime.h>
#include <math.h>

typedef __bf16 bf16_t;
typedef __bf16 bf16x8 __attribute__((ext_vector_type(8)));
typedef float f32x4 __attribute__((ext_vector_type(4)));
typedef int i32x4 __attribute__((ext_vector_type(4)));
typedef unsigned int u32;

#define HID 2048
#define NBATCH 16
#define SEQLEN 512
#define MTOT (NBATCH * SEQLEN)
#define NBLK 64
#define RTHREADS 512
#define LN_EPS 1e-5f
#define STBUF_DWORDS (NBATCH * HID)   // 32768 u32 per state buffer

// ================= GEMM: inp = x @ Wi^T + b  -> d_out (fp32) =================
// Also zeroes the tagged-state buffers (both ping-pong copies) EVERY launch,
// so graph replays never see stale tags from a previous invocation.
__global__ __launch_bounds__(256) void gemm_proj(
    const float* __restrict__ X,
    const float* __restrict__ Wi,
    const float* __restrict__ bias,
    float* __restrict__ C,
    u32* __restrict__ st)
{
    __shared__ bf16_t lA[128 * 32];
    __shared__ bf16_t lB[128 * 32];
    const int tid = threadIdx.x;
    if (blockIdx.y == 0) {
        // 16 blocks x 256 thr zero 2*32768 dwords (16 each, coalesced)
        const int base = blockIdx.x * 256 + tid;
#pragma unroll
        for (int j = 0; j < 16; ++j)
            st[j * 4096 + base] = 0u;
    }
    const int lane = tid & 63;
    const int wv = tid >> 6;
    const int bn = blockIdx.x * 128;
    const int bm = blockIdx.y * 128;
    const int wr = (wv >> 1) * 64;
    const int wc = (wv & 1) * 64;

    f32x4 zero = {0.f, 0.f, 0.f, 0.f};
    f32x4 acc[4][4];
#pragma unroll
    for (int i = 0; i < 4; ++i)
#pragma unroll
        for (int j = 0; j < 4; ++j) acc[i][j] = zero;

    for (int k0 = 0; k0 < HID; k0 += 32) {
        __syncthreads();
#pragma unroll
        for (int c = 0; c < 2; ++c) {
            const int chunk = c * 256 + tid;      // 0..511
            const int row = chunk >> 2;           // 0..127
            const int kp = (chunk & 3) ^ (row & 3); // XOR-swizzled source chunk
            {
                const float* s = X + (size_t)(bm + row) * HID + k0 + kp * 8;
                float4 a0 = *(const float4*)s;
                float4 a1 = *(const float4*)(s + 4);
                bf16x8 v;
                v[0] = (bf16_t)a0.x; v[1] = (bf16_t)a0.y; v[2] = (bf16_t)a0.z; v[3] = (bf16_t)a0.w;
                v[4] = (bf16_t)a1.x; v[5] = (bf16_t)a1.y; v[6] = (bf16_t)a1.z; v[7] = (bf16_t)a1.w;
                *(bf16x8*)(lA + chunk * 8) = v;
            }
            {
                const float* s = Wi + (size_t)(bn + row) * HID + k0 + kp * 8;
                float4 a0 = *(const float4*)s;
                float4 a1 = *(const float4*)(s + 4);
                bf16x8 v;
                v[0] = (bf16_t)a0.x; v[1] = (bf16_t)a0.y; v[2] = (bf16_t)a0.z; v[3] = (bf16_t)a0.w;
                v[4] = (bf16_t)a1.x; v[5] = (bf16_t)a1.y; v[6] = (bf16_t)a1.z; v[7] = (bf16_t)a1.w;
                *(bf16x8*)(lB + chunk * 8) = v;
            }
        }
        __syncthreads();

        bf16x8 af[4], bfr[4];
#pragma unroll
        for (int i = 0; i < 4; ++i) {
            const int row = wr + i * 16 + (lane & 15);
            const int ck = (lane >> 4) ^ (row & 3);
            af[i] = *(const bf16x8*)(lA + row * 32 + ck * 8);
        }
#pragma unroll
        for (int j = 0; j < 4; ++j) {
            const int row = wc + j * 16 + (lane & 15);
            const int ck = (lane >> 4) ^ (row & 3);
            bfr[j] = *(const bf16x8*)(lB + row * 32 + ck * 8);
        }
#pragma unroll
        for (int i = 0; i < 4; ++i)
#pragma unroll
            for (int j = 0; j < 4; ++j)
                acc[i][j] = __builtin_amdgcn_mfma_f32_16x16x32_bf16(af[i], bfr[j], acc[i][j], 0, 0, 0);
    }

#pragma unroll
    for (int j = 0; j < 4; ++j) {
        const int col = bn + wc + j * 16 + (lane & 15);
        const float bv = bias[col];
#pragma unroll
        for (int i = 0; i < 4; ++i) {
#pragma unroll
            for (int r = 0; r < 4; ++r) {
                const int row = bm + wr + i * 16 + (lane >> 4) * 4 + r;
                C[(size_t)row * HID + col] = acc[i][j][r] + bv;
            }
        }
    }
}

// ================= Persistent recurrent kernel =================
// Tagged-data sync: state element = u32 (low16 = bf16 value, high16 = step
// tag). Producers fire ONE relaxed agent-scope store per thread (no drain, no
// flags). Consumers poll the data itself (L2-bypass dwordx4 sc0 sc1) until
// every dword's tag == t. Ping-pong buf[t&1]; tag written at step t is t+1,
// so the 2-step reuse window always has distinct tags (t+1 vs t-1) and the
// 0xAAAA poison/zero never matches. Overwrite-vs-reader race closed by: a
// block stores step t+1 only after its LDS barrier joined all 8 waves, whose
// wait(t+1) union covers all 64 blocks; a block shows tag t+1 only after ALL
// its waves finished their step-t reads (store phase is post-barrier).
__global__ __launch_bounds__(RTHREADS, 1) void recurrent(
    const float* __restrict__ Wr,
    const float* __restrict__ mask,
    const float* __restrict__ tau,
    float* __restrict__ io,      // d_out: holds inp (read rows t+1) -> states (write row t)
    u32* __restrict__ stA,
    u32* __restrict__ stB)
{
    const int tid = threadIdx.x;
    const int lane = tid & 63;
    const int wv = tid >> 6;          // K-eighth 0..7
    const int colbase = blockIdx.x * 32;

    __shared__ float red[8 * 528];    // [kq][batch][col] stride-33 padded

    // ---- preload masked recurrent weights as MFMA B-fragments (VGPR-resident) ----
    bf16x8 wf0[8], wf1[8];
    {
        const int kb = wv * 256 + (lane >> 4) * 8;
#pragma unroll
        for (int ct = 0; ct < 2; ++ct) {
            const int gc = colbase + ct * 16 + (lane & 15);
#pragma unroll
            for (int ks = 0; ks < 8; ++ks) {
                const size_t off = (size_t)gc * HID + kb + ks * 32;
                float4 a0 = *(const float4*)(Wr + off);
                float4 a1 = *(const float4*)(Wr + off + 4);
                float4 m0 = *(const float4*)(mask + off);
                float4 m1 = *(const float4*)(mask + off + 4);
                bf16x8 v;
                v[0] = (bf16_t)(a0.x * m0.x); v[1] = (bf16_t)(a0.y * m0.y);
                v[2] = (bf16_t)(a0.z * m0.z); v[3] = (bf16_t)(a0.w * m0.w);
                v[4] = (bf16_t)(a1.x * m1.x); v[5] = (bf16_t)(a1.y * m1.y);
                v[6] = (bf16_t)(a1.z * m1.z); v[7] = (bf16_t)(a1.w * m1.w);
                if (ct == 0) wf0[ks] = v; else wf1[ks] = v;
            }
        }
    }

    // update-thread mapping: 512 threads <-> 16 batches x 32 cols (1 dword each)
    const int ub = tid >> 5;
    const int uc = tid & 31;
    const int ugc = colbase + uc;
    float alpha;
    {
        float tv = tau[ugc];
        tv = fminf(fmaxf(tv, 1.0f), 20.0f);
        alpha = fminf(fmaxf(0.5f / tv, 0.0f), 1.0f);
    }

    float s_old = 0.f;
    float cur_inp = io[(size_t)ub * (SEQLEN * HID) + ugc];

    const int arow = lane & 15;                     // batch row of A fragment
    const int akb = wv * 256 + (lane >> 4) * 8;     // k offset of A fragment

    u32* cur = stA;   // step t reads buf[(t-1)&1]; step 0 writes stA
    u32* nxt = stB;

    // ---- step 0: state is zero -> rec = 0; tagged store (tag 1), no drain ----
    {
        float z = fminf(fmaxf(cur_inp, -15.f), 15.f);
        const float e = __expf(2.0f * z);
        const float tgt = (e - 1.0f) / (e + 1.0f);
        float sn = alpha * tgt;                         // s_old == 0
        sn = fminf(fmaxf(sn, -1.0f), 1.0f);
        bf16_t b = (bf16_t)sn;
        union { bf16_t b2[2]; u32 u; } pv; pv.b2[0] = b; pv.b2[1] = (bf16_t)0.f;
        const u32 stv = (pv.u & 0xffffu) | (1u << 16);
        __hip_atomic_store(cur + (size_t)ub * HID + ugc, stv,
                           __ATOMIC_RELAXED, __HIP_MEMORY_SCOPE_AGENT);
        io[(size_t)ub * (SEQLEN * HID) + ugc] = sn;     // pre-LN output row 0
        s_old = sn;
        cur_inp = io[(size_t)ub * (SEQLEN * HID) + HID + ugc];  // row 1 (still GEMM data)
    }

    for (int t = 1; t < SEQLEN; ++t) {
        const int tg = t;
        const int tgs = tg << 16;
        const u32* tb = cur + (size_t)arow * HID + akb;

        // ---- fat poll: load fragments, verify every dword's tag == t ----
        i32x4 qa0, qa1, qa2, qa3, qa4, qa5, qa6, qa7;
        i32x4 qb0, qb1, qb2, qb3, qb4, qb5, qb6, qb7;
        for (;;) {
            asm volatile("global_load_dwordx4 %0, %1, off sc0 sc1"            : "=v"(qa0) : "v"(tb) : "memory");
            asm volatile("global_load_dwordx4 %0, %1, off offset:16 sc0 sc1"  : "=v"(qb0) : "v"(tb) : "memory");
            asm volatile("global_load_dwordx4 %0, %1, off offset:128 sc0 sc1" : "=v"(qa1) : "v"(tb) : "memory");
            asm volatile("global_load_dwordx4 %0, %1, off offset:144 sc0 sc1" : "=v"(qb1) : "v"(tb) : "memory");
            asm volatile("global_load_dwordx4 %0, %1, off offset:256 sc0 sc1" : "=v"(qa2) : "v"(tb) : "memory");
            asm volatile("global_load_dwordx4 %0, %1, off offset:272 sc0 sc1" : "=v"(qb2) : "v"(tb) : "memory");
            asm volatile("global_load_dwordx4 %0, %1, off offset:384 sc0 sc1" : "=v"(qa3) : "v"(tb) : "memory");
            asm volatile("global_load_dwordx4 %0, %1, off offset:400 sc0 sc1" : "=v"(qb3) : "v"(tb) : "memory");
            asm volatile("global_load_dwordx4 %0, %1, off offset:512 sc0 sc1" : "=v"(qa4) : "v"(tb) : "memory");
            asm volatile("global_load_dwordx4 %0, %1, off offset:528 sc0 sc1" : "=v"(qb4) : "v"(tb) : "memory");
            asm volatile("global_load_dwordx4 %0, %1, off offset:640 sc0 sc1" : "=v"(qa5) : "v"(tb) : "memory");
            asm volatile("global_load_dwordx4 %0, %1, off offset:656 sc0 sc1" : "=v"(qb5) : "v"(tb) : "memory");
            asm volatile("global_load_dwordx4 %0, %1, off offset:768 sc0 sc1" : "=v"(qa6) : "v"(tb) : "memory");
            asm volatile("global_load_dwordx4 %0, %1, off offset:784 sc0 sc1" : "=v"(qb6) : "v"(tb) : "memory");
            asm volatile("global_load_dwordx4 %0, %1, off offset:896 sc0 sc1" : "=v"(qa7) : "v"(tb) : "memory");
            asm volatile("global_load_dwordx4 %0, %1, off offset:912 sc0 sc1" : "=v"(qb7) : "v"(tb) : "memory");
            asm volatile("s_waitcnt vmcnt(0)" ::: "memory");

            int bad;
#define TC(q) (((q)[0] ^ tgs) | ((q)[1] ^ tgs) | ((q)[2] ^ tgs) | ((q)[3] ^ tgs))
            bad  = TC(qa0) | TC(qb0) | TC(qa1) | TC(qb1);
            bad |= TC(qa2) | TC(qb2) | TC(qa3) | TC(qb3);
            bad |= TC(qa4) | TC(qb4) | TC(qa5) | TC(qb5);
            bad |= TC(qa6) | TC(qb6) | TC(qa7) | TC(qb7);
#undef TC
            if (__ballot((bad & (int)0xffff0000) != 0) == 0ull) break;

            // cheap spin on one dword until fresh, then retry the fat load
            int v;
            do {
                asm volatile("global_load_dword %0, %1, off sc0 sc1\n\ts_waitcnt vmcnt(0)"
                             : "=v"(v) : "v"(tb) : "memory");
            } while (__ballot((v >> 16) != tg) != 0ull);
        }

        // ---- pack tagged dwords -> bf16x8 fragments ----
#define PK(lo_, hi_) (((lo_) & 0xffff) | ((hi_) << 16))
        union uf { int d[4]; bf16x8 v; };
        uf a0_, a1_, a2_, a3_, a4_, a5_, a6_, a7_;
#define PACK(dst, qa, qb) \
        dst.d[0] = PK(qa[0], qa[1]); dst.d[1] = PK(qa[2], qa[3]); \
        dst.d[2] = PK(qb[0], qb[1]); dst.d[3] = PK(qb[2], qb[3]);
        PACK(a0_, qa0, qb0) PACK(a1_, qa1, qb1) PACK(a2_, qa2, qb2) PACK(a3_, qa3, qb3)
        PACK(a4_, qa4, qb4) PACK(a5_, qa5, qb5) PACK(a6_, qa6, qb6) PACK(a7_, qa7, qb7)
#undef PACK
#undef PK

        // ---- matvec partial: 4 independent MFMA chains ----
        f32x4 c0 = {0.f,0.f,0.f,0.f}, c1 = {0.f,0.f,0.f,0.f};
        f32x4 c2 = {0.f,0.f,0.f,0.f}, c3 = {0.f,0.f,0.f,0.f};
        c0 = __builtin_amdgcn_mfma_f32_16x16x32_bf16(a0_.v, wf0[0], c0, 0, 0, 0);
        c1 = __builtin_amdgcn_mfma_f32_16x16x32_bf16(a1_.v, wf0[1], c1, 0, 0, 0);
        c2 = __builtin_amdgcn_mfma_f32_16x16x32_bf16(a0_.v, wf1[0], c2, 0, 0, 0);
        c3 = __builtin_amdgcn_mfma_f32_16x16x32_bf16(a1_.v, wf1[1], c3, 0, 0, 0);
        c0 = __builtin_amdgcn_mfma_f32_16x16x32_bf16(a2_.v, wf0[2], c0, 0, 0, 0);
        c1 = __builtin_amdgcn_mfma_f32_16x16x32_bf16(a3_.v, wf0[3], c1, 0, 0, 0);
        c2 = __builtin_amdgcn_mfma_f32_16x16x32_bf16(a2_.v, wf1[2], c2, 0, 0, 0);
        c3 = __builtin_amdgcn_mfma_f32_16x16x32_bf16(a3_.v, wf1[3], c3, 0, 0, 0);
        c0 = __builtin_amdgcn_mfma_f32_16x16x32_bf16(a4_.v, wf0[4], c0, 0, 0, 0);
        c1 = __builtin_amdgcn_mfma_f32_16x16x32_bf16(a5_.v, wf0[5], c1, 0, 0, 0);
        c2 = __builtin_amdgcn_mfma_f32_16x16x32_bf16(a4_.v, wf1[4], c2, 0, 0, 0);
        c3 = __builtin_amdgcn_mfma_f32_16x16x32_bf16(a5_.v, wf1[5], c3, 0, 0, 0);
        c0 = __builtin_amdgcn_mfma_f32_16x16x32_bf16(a6_.v, wf0[6], c0, 0, 0, 0);
        c1 = __builtin_amdgcn_mfma_f32_16x16x32_bf16(a7_.v, wf0[7], c1, 0, 0, 0);
        c2 = __builtin_amdgcn_mfma_f32_16x16x32_bf16(a6_.v, wf1[6], c2, 0, 0, 0);
        c3 = __builtin_amdgcn_mfma_f32_16x16x32_bf16(a7_.v, wf1[7], c3, 0, 0, 0);
        f32x4 accA = c0 + c1;   // ct=0 partial (16 cols)
        f32x4 accB = c2 + c3;   // ct=1 partial

        // ---- C: all waves finished READING red (iter t-1) before overwrite ----
        __syncthreads();
        {
            const int colA = lane & 15;
            const int colB = 16 + (lane & 15);
            const int r0 = (lane >> 4) * 4;
            const int base = wv * 528;
#pragma unroll
            for (int r = 0; r < 4; ++r) {
                red[base + (r0 + r) * 33 + colA] = accA[r];
                red[base + (r0 + r) * 33 + colB] = accB[r];
            }
        }
        __syncthreads();   // B
        float rec = 0.f;
#pragma unroll
        for (int q = 0; q < 8; ++q)
            rec += red[q * 528 + ub * 33 + uc];

        // ---- fused update: tanh + EMA + clip ----
        float z = cur_inp + rec;
        z = fminf(fmaxf(z, -15.f), 15.f);
        const float e = __expf(2.0f * z);
        const float tgt = (e - 1.0f) / (e + 1.0f);
        float sn = s_old + alpha * (tgt - s_old);
        sn = fminf(fmaxf(sn, -1.0f), 1.0f);

        // ---- tagged state store: ONE dword, fire-and-forget ----
        if (t != SEQLEN - 1) {
            bf16_t b = (bf16_t)sn;
            union { bf16_t b2[2]; u32 u; } pv; pv.b2[0] = b; pv.b2[1] = (bf16_t)0.f;
            const u32 stv = (pv.u & 0xffffu) | ((u32)(t + 1) << 16);
            __hip_atomic_store(nxt + (size_t)ub * HID + ugc, stv,
                               __ATOMIC_RELAXED, __HIP_MEMORY_SCOPE_AGENT);
        }

        // ---- off-critical-path: pre-LN output + next input prefetch ----
        io[(size_t)ub * (SEQLEN * HID) + (size_t)t * HID + ugc] = sn;
        const int tn = (t < SEQLEN - 1) ? (t + 1) : t;
        cur_inp = io[(size_t)ub * (SEQLEN * HID) + (size_t)tn * HID + ugc];
        s_old = sn;
        u32* tmp = cur; cur = nxt; nxt = tmp;
    }
}

// ================= LayerNorm (in-place on d_out) =================
__global__ __launch_bounds__(256) void ln_kernel(
    float* __restrict__ io,
    const float* __restrict__ gamma,
    const float* __restrict__ beta)
{
    const size_t row = blockIdx.x;
    float* p = io + row * HID;
    const int tid = threadIdx.x;
    float4 v0 = *(const float4*)(p + tid * 4);
    float4 v1 = *(const float4*)(p + 1024 + tid * 4);
    float s  = v0.x + v0.y + v0.z + v0.w + v1.x + v1.y + v1.z + v1.w;
    float ss = v0.x * v0.x + v0.y * v0.y + v0.z * v0.z + v0.w * v0.w
             + v1.x * v1.x + v1.y * v1.y + v1.z * v1.z + v1.w * v1.w;
#pragma unroll
    for (int off = 32; off > 0; off >>= 1) {
        s  += __shfl_down(s, off, 64);
        ss += __shfl_down(ss, off, 64);
    }
    __shared__ float rs[4], rss[4];
    if ((tid & 63) == 0) { rs[tid >> 6] = s; rss[tid >> 6] = ss; }
    __syncthreads();
    s  = rs[0] + rs[1] + rs[2] + rs[3];
    ss = rss[0] + rss[1] + rss[2] + rss[3];
    const float mu = s * (1.f / HID);
    const float var = ss * (1.f / HID) - mu * mu;
    const float inv = rsqrtf(var + LN_EPS);
    const int c0 = tid * 4, c1 = 1024 + tid * 4;
    float4 g0 = *(const float4*)(gamma + c0);
    float4 g1 = *(const float4*)(gamma + c1);
    float4 b0 = *(const float4*)(beta + c0);
    float4 b1 = *(const float4*)(beta + c1);
    float4 o0, o1;
    o0.x = (v0.x - mu) * inv * g0.x + b0.x;
    o0.y = (v0.y - mu) * inv * g0.y + b0.y;
    o0.z = (v0.z - mu) * inv * g0.z + b0.z;
    o0.w = (v0.w - mu) * inv * g0.w + b0.w;
    o1.x = (v1.x - mu) * inv * g1.x + b1.x;
    o1.y = (v1.y - mu) * inv * g1.y + b1.y;
    o1.z = (v1.z - mu) * inv * g1.z + b1.z;
    o1.w = (v1.w - mu) * inv * g1.w + b1.w;
    *(float4*)(p + tid * 4) = o0;
    *(float4*)(p + 1024 + tid * 4) = o1;
}

extern "C" void kernel_launch(void* const* d_in, const int* in_sizes, int n_in,
                              void* d_out, int out_size, void* d_ws, size_t ws_size,
                              hipStream_t stream)
{
    const float* x     = (const float*)d_in[0];
    const float* Wi    = (const float*)d_in[1];
    const float* bias  = (const float*)d_in[2];
    const float* Wr    = (const float*)d_in[3];
    const float* mask  = (const float*)d_in[4];
    const float* tau   = (const float*)d_in[5];
    const float* gamma = (const float*)d_in[6];
    const float* beta  = (const float*)d_in[7];
    float* out = (float*)d_out;

    u32* stA = (u32*)d_ws;
    u32* stB = stA + STBUF_DWORDS;

    // 1) input projection -> d_out rows hold inp[b,t,:] (fp32); zeroes tags
    gemm_proj<<<dim3(16, 64), 256, 0, stream>>>(x, Wi, bias, out, stA);
    // 2) persistent recurrence: overwrites d_out rows with pre-LN states
    recurrent<<<NBLK, RTHREADS, 0, stream>>>(Wr, mask, tau, out, stA, stB);
    // 3) layernorm in-place
    ln_kernel<<<MTOT, 256, 0, stream>>>(out, gamma, beta);
}

// Round 7
// 2223.477 us; speedup vs baseline: 2.3894x; 2.3894x over previous
//
#include <hip/hip_runtime.h>
#include <math.h>

typedef __bf16 bf16_t;
typedef __bf16 bf16x8 __attribute__((ext_vector_type(8)));
typedef float f32x4 __attribute__((ext_vector_type(4)));
typedef int i32x4 __attribute__((ext_vector_type(4)));
typedef unsigned int u32;

#define HID 2048
#define NBATCH 16
#define SEQLEN 512
#define MTOT (NBATCH * SEQLEN)
#define NBLK 32
#define RTHREADS 256
#define LN_EPS 1e-5f

// ================= GEMM: inp = x @ Wi^T + b  -> d_out (fp32) =================
__global__ __launch_bounds__(256) void gemm_proj(
    const float* __restrict__ X,
    const float* __restrict__ Wi,
    const float* __restrict__ bias,
    float* __restrict__ C,
    int* __restrict__ flags)
{
    __shared__ bf16_t lA[128 * 32];
    __shared__ bf16_t lB[128 * 32];
    const int tid = threadIdx.x;
    if (blockIdx.x == 0 && blockIdx.y == 0) {
        if (tid < NBLK) flags[tid] = 0;   // re-zero EVERY launch (graph replay safety)
    }
    const int lane = tid & 63;
    const int wv = tid >> 6;
    const int bn = blockIdx.x * 128;
    const int bm = blockIdx.y * 128;
    const int wr = (wv >> 1) * 64;
    const int wc = (wv & 1) * 64;

    f32x4 zero = {0.f, 0.f, 0.f, 0.f};
    f32x4 acc[4][4];
#pragma unroll
    for (int i = 0; i < 4; ++i)
#pragma unroll
        for (int j = 0; j < 4; ++j) acc[i][j] = zero;

    for (int k0 = 0; k0 < HID; k0 += 32) {
        __syncthreads();
#pragma unroll
        for (int c = 0; c < 2; ++c) {
            const int chunk = c * 256 + tid;      // 0..511
            const int row = chunk >> 2;           // 0..127
            const int kp = (chunk & 3) ^ (row & 3); // XOR-swizzled source chunk
            {
                const float* s = X + (size_t)(bm + row) * HID + k0 + kp * 8;
                float4 a0 = *(const float4*)s;
                float4 a1 = *(const float4*)(s + 4);
                bf16x8 v;
                v[0] = (bf16_t)a0.x; v[1] = (bf16_t)a0.y; v[2] = (bf16_t)a0.z; v[3] = (bf16_t)a0.w;
                v[4] = (bf16_t)a1.x; v[5] = (bf16_t)a1.y; v[6] = (bf16_t)a1.z; v[7] = (bf16_t)a1.w;
                *(bf16x8*)(lA + chunk * 8) = v;
            }
            {
                const float* s = Wi + (size_t)(bn + row) * HID + k0 + kp * 8;
                float4 a0 = *(const float4*)s;
                float4 a1 = *(const float4*)(s + 4);
                bf16x8 v;
                v[0] = (bf16_t)a0.x; v[1] = (bf16_t)a0.y; v[2] = (bf16_t)a0.z; v[3] = (bf16_t)a0.w;
                v[4] = (bf16_t)a1.x; v[5] = (bf16_t)a1.y; v[6] = (bf16_t)a1.z; v[7] = (bf16_t)a1.w;
                *(bf16x8*)(lB + chunk * 8) = v;
            }
        }
        __syncthreads();

        bf16x8 af[4], bfr[4];
#pragma unroll
        for (int i = 0; i < 4; ++i) {
            const int row = wr + i * 16 + (lane & 15);
            const int ck = (lane >> 4) ^ (row & 3);
            af[i] = *(const bf16x8*)(lA + row * 32 + ck * 8);
        }
#pragma unroll
        for (int j = 0; j < 4; ++j) {
            const int row = wc + j * 16 + (lane & 15);
            const int ck = (lane >> 4) ^ (row & 3);
            bfr[j] = *(const bf16x8*)(lB + row * 32 + ck * 8);
        }
#pragma unroll
        for (int i = 0; i < 4; ++i)
#pragma unroll
            for (int j = 0; j < 4; ++j)
                acc[i][j] = __builtin_amdgcn_mfma_f32_16x16x32_bf16(af[i], bfr[j], acc[i][j], 0, 0, 0);
    }

#pragma unroll
    for (int j = 0; j < 4; ++j) {
        const int col = bn + wc + j * 16 + (lane & 15);
        const float bv = bias[col];
#pragma unroll
        for (int i = 0; i < 4; ++i) {
#pragma unroll
            for (int r = 0; r < 4; ++r) {
                const int row = bm + wr + i * 16 + (lane >> 4) * 4 + r;
                C[(size_t)row * HID + col] = acc[i][j][r] + bv;
            }
        }
    }
}

// ================= Persistent recurrent kernel =================
// 32 blocks x 256 thr (4 waves); block owns 64 output cols; wave = K-quarter.
// Per wave: 64 B-frags (4 col-tiles x 16 K-frags) VGPR-resident; per step 16
// A-frag dwordx4 loads (counted vmcnt split) + 64 MFMA; 4-wave LDS reduce.
// Sync protocol (R4, best measured): publish own flag after loop-top
// __syncthreads (compiler drains vmcnt -> prev stores at L3); wave 0 polls all
// 32 flags (ONE cache line); state moves via packed-u32 relaxed agent-scope
// stores / sc0 sc1 dwordx4 loads. Ping-pong safety: flags>=t implies all
// blocks finished iter t-1 reads, so writing buffer(t)=buffer(t-2) is safe.
__global__ __launch_bounds__(RTHREADS, 1) void recurrent(
    const float* __restrict__ Wr,
    const float* __restrict__ mask,
    const float* __restrict__ tau,
    float* __restrict__ io,      // d_out: holds inp (read rows t+1) -> states (write row t)
    bf16_t* __restrict__ st0,
    bf16_t* __restrict__ st1,
    int* __restrict__ flags)     // [32]
{
    const int tid = threadIdx.x;
    const int lane = tid & 63;
    const int wv = tid >> 6;          // K-quarter 0..3
    const int colbase = blockIdx.x * 64;

    __shared__ float red[4][16][68];  // [kq][batch][col] pad 68

    // ---- preload masked weights: 64 MFMA B-fragments per wave (256 VGPR) ----
    bf16x8 wf[64];
    {
        const int kb = wv * 512 + (lane >> 4) * 8;
#pragma unroll
        for (int ct = 0; ct < 4; ++ct) {
            const int gc = colbase + ct * 16 + (lane & 15);
#pragma unroll
            for (int kf = 0; kf < 16; ++kf) {
                const size_t off = (size_t)gc * HID + kb + kf * 32;
                float4 a0 = *(const float4*)(Wr + off);
                float4 a1 = *(const float4*)(Wr + off + 4);
                float4 m0 = *(const float4*)(mask + off);
                float4 m1 = *(const float4*)(mask + off + 4);
                bf16x8 v;
                v[0] = (bf16_t)(a0.x * m0.x); v[1] = (bf16_t)(a0.y * m0.y);
                v[2] = (bf16_t)(a0.z * m0.z); v[3] = (bf16_t)(a0.w * m0.w);
                v[4] = (bf16_t)(a1.x * m1.x); v[5] = (bf16_t)(a1.y * m1.y);
                v[6] = (bf16_t)(a1.z * m1.z); v[7] = (bf16_t)(a1.w * m1.w);
                wf[ct * 16 + kf] = v;
            }
        }
    }

    // update mapping: 256 threads <-> 16 batches x 16 col-groups of 4
    const int row = tid >> 4;          // batch 0..15
    const int cg  = (tid & 15) * 4;    // col offset within block
    const int gcol = colbase + cg;
    float al[4];
#pragma unroll
    for (int j = 0; j < 4; ++j) {
        float tv = tau[gcol + j];
        tv = fminf(fmaxf(tv, 1.0f), 20.0f);
        al[j] = fminf(fmaxf(0.5f / tv, 0.0f), 1.0f);
    }

    float s_old[4] = {0.f, 0.f, 0.f, 0.f};
    union F4 { float4 v; float f[4]; };
    F4 cin; cin.v = *(const float4*)(io + (size_t)row * (SEQLEN * HID) + gcol);

    const int akb = wv * 512 + (lane >> 4) * 8;   // A-frag k offset
    bf16_t* cur = st0;
    bf16_t* nxt = st1;

    // ---- step 0: state zero -> rec = 0 ----
    {
        float sn[4]; F4 ov;
#pragma unroll
        for (int j = 0; j < 4; ++j) {
            float z = fminf(fmaxf(cin.f[j], -15.f), 15.f);
            const float e = __expf(2.0f * z);
            const float tg = (e - 1.0f) / (e + 1.0f);
            float s = al[j] * tg;
            s = fminf(fmaxf(s, -1.0f), 1.0f);
            sn[j] = s; ov.f[j] = s;
        }
        union { bf16_t b[2]; u32 u; } p0, p1;
        p0.b[0] = (bf16_t)sn[0]; p0.b[1] = (bf16_t)sn[1];
        p1.b[0] = (bf16_t)sn[2]; p1.b[1] = (bf16_t)sn[3];
        u32* sp = (u32*)(nxt + (size_t)row * HID + gcol);
        __hip_atomic_store(sp,     p0.u, __ATOMIC_RELAXED, __HIP_MEMORY_SCOPE_AGENT);
        __hip_atomic_store(sp + 1, p1.u, __ATOMIC_RELAXED, __HIP_MEMORY_SCOPE_AGENT);
        *(float4*)(io + (size_t)row * (SEQLEN * HID) + gcol) = ov.v;
#pragma unroll
        for (int j = 0; j < 4; ++j) s_old[j] = sn[j];
        cin.v = *(const float4*)(io + (size_t)row * (SEQLEN * HID) + HID + gcol);
        bf16_t* tmp = cur; cur = nxt; nxt = tmp;
    }

    for (int t = 1; t < SEQLEN; ++t) {
        // ---- loop-top join: drains vmcnt -> step-(t-1) state stores at L3 ----
        __syncthreads();
        if (tid == 0)
            __hip_atomic_store(flags + (int)blockIdx.x, t,
                               __ATOMIC_RELAXED, __HIP_MEMORY_SCOPE_AGENT);
        if (wv == 0) {
            int v;
            do {
                v = __hip_atomic_load(flags + (lane & 31),
                                      __ATOMIC_RELAXED, __HIP_MEMORY_SCOPE_AGENT);
            } while (__ballot(v < t) != 0ull);
        }
        __syncthreads();   // release other waves once data is globally ready

        // ---- device-coherent A-fragment loads (16 x 16B, counted vmcnt) ----
        const bf16_t* ab = cur + (size_t)(lane & 15) * HID + akb;
        union uf { i32x4 i; bf16x8 v; } a[16];
        asm volatile("global_load_dwordx4 %0, %1, off sc0 sc1"            : "=v"(a[0].i)  : "v"(ab) : "memory");
        asm volatile("global_load_dwordx4 %0, %1, off offset:64 sc0 sc1"  : "=v"(a[1].i)  : "v"(ab) : "memory");
        asm volatile("global_load_dwordx4 %0, %1, off offset:128 sc0 sc1" : "=v"(a[2].i)  : "v"(ab) : "memory");
        asm volatile("global_load_dwordx4 %0, %1, off offset:192 sc0 sc1" : "=v"(a[3].i)  : "v"(ab) : "memory");
        asm volatile("global_load_dwordx4 %0, %1, off offset:256 sc0 sc1" : "=v"(a[4].i)  : "v"(ab) : "memory");
        asm volatile("global_load_dwordx4 %0, %1, off offset:320 sc0 sc1" : "=v"(a[5].i)  : "v"(ab) : "memory");
        asm volatile("global_load_dwordx4 %0, %1, off offset:384 sc0 sc1" : "=v"(a[6].i)  : "v"(ab) : "memory");
        asm volatile("global_load_dwordx4 %0, %1, off offset:448 sc0 sc1" : "=v"(a[7].i)  : "v"(ab) : "memory");
        asm volatile("global_load_dwordx4 %0, %1, off offset:512 sc0 sc1" : "=v"(a[8].i)  : "v"(ab) : "memory");
        asm volatile("global_load_dwordx4 %0, %1, off offset:576 sc0 sc1" : "=v"(a[9].i)  : "v"(ab) : "memory");
        asm volatile("global_load_dwordx4 %0, %1, off offset:640 sc0 sc1" : "=v"(a[10].i) : "v"(ab) : "memory");
        asm volatile("global_load_dwordx4 %0, %1, off offset:704 sc0 sc1" : "=v"(a[11].i) : "v"(ab) : "memory");
        asm volatile("global_load_dwordx4 %0, %1, off offset:768 sc0 sc1" : "=v"(a[12].i) : "v"(ab) : "memory");
        asm volatile("global_load_dwordx4 %0, %1, off offset:832 sc0 sc1" : "=v"(a[13].i) : "v"(ab) : "memory");
        asm volatile("global_load_dwordx4 %0, %1, off offset:896 sc0 sc1" : "=v"(a[14].i) : "v"(ab) : "memory");
        asm volatile("global_load_dwordx4 %0, %1, off offset:960 sc0 sc1" : "=v"(a[15].i) : "v"(ab) : "memory");

        f32x4 acc0 = {0.f,0.f,0.f,0.f}, acc1 = {0.f,0.f,0.f,0.f};
        f32x4 acc2 = {0.f,0.f,0.f,0.f}, acc3 = {0.f,0.f,0.f,0.f};

        asm volatile("s_waitcnt vmcnt(8)" ::: "memory");
        __builtin_amdgcn_sched_barrier(0);
#define MF(kf) \
        acc0 = __builtin_amdgcn_mfma_f32_16x16x32_bf16(a[kf].v, wf[kf],      acc0, 0, 0, 0); \
        acc1 = __builtin_amdgcn_mfma_f32_16x16x32_bf16(a[kf].v, wf[16 + kf], acc1, 0, 0, 0); \
        acc2 = __builtin_amdgcn_mfma_f32_16x16x32_bf16(a[kf].v, wf[32 + kf], acc2, 0, 0, 0); \
        acc3 = __builtin_amdgcn_mfma_f32_16x16x32_bf16(a[kf].v, wf[48 + kf], acc3, 0, 0, 0);
        MF(0) MF(1) MF(2) MF(3) MF(4) MF(5) MF(6) MF(7)
        asm volatile("s_waitcnt vmcnt(0)" ::: "memory");
        __builtin_amdgcn_sched_barrier(0);
        MF(8) MF(9) MF(10) MF(11) MF(12) MF(13) MF(14) MF(15)
#undef MF

        // ---- LDS partials (prev-iter reads finished before loop-top barrier) ----
        {
            const int r0 = (lane >> 4) * 4;
            const int cA = lane & 15;
#pragma unroll
            for (int r = 0; r < 4; ++r) {
                red[wv][r0 + r][cA]      = acc0[r];
                red[wv][r0 + r][16 + cA] = acc1[r];
                red[wv][r0 + r][32 + cA] = acc2[r];
                red[wv][r0 + r][48 + cA] = acc3[r];
            }
        }
        __syncthreads();

        F4 s0, s1, s2, s3;
        s0.v = *(const float4*)&red[0][row][cg];
        s1.v = *(const float4*)&red[1][row][cg];
        s2.v = *(const float4*)&red[2][row][cg];
        s3.v = *(const float4*)&red[3][row][cg];

        float sn[4]; F4 ov;
#pragma unroll
        for (int j = 0; j < 4; ++j) {
            const float rec = s0.f[j] + s1.f[j] + s2.f[j] + s3.f[j];
            float z = cin.f[j] + rec;
            z = fminf(fmaxf(z, -15.f), 15.f);
            const float e = __expf(2.0f * z);
            const float tg = (e - 1.0f) / (e + 1.0f);
            float s = s_old[j] + al[j] * (tg - s_old[j]);
            s = fminf(fmaxf(s, -1.0f), 1.0f);
            sn[j] = s; ov.f[j] = s;
        }

        // ---- packed state stores (agent scope, write-through) ----
        union { bf16_t b[2]; u32 u; } p0, p1;
        p0.b[0] = (bf16_t)sn[0]; p0.b[1] = (bf16_t)sn[1];
        p1.b[0] = (bf16_t)sn[2]; p1.b[1] = (bf16_t)sn[3];
        u32* sp = (u32*)(nxt + (size_t)row * HID + gcol);
        __hip_atomic_store(sp,     p0.u, __ATOMIC_RELAXED, __HIP_MEMORY_SCOPE_AGENT);
        __hip_atomic_store(sp + 1, p1.u, __ATOMIC_RELAXED, __HIP_MEMORY_SCOPE_AGENT);

        // ---- off-critical-path: pre-LN output + next input prefetch ----
        *(float4*)(io + (size_t)row * (SEQLEN * HID) + (size_t)t * HID + gcol) = ov.v;
        const int tn = (t < SEQLEN - 1) ? (t + 1) : t;
        cin.v = *(const float4*)(io + (size_t)row * (SEQLEN * HID) + (size_t)tn * HID + gcol);
#pragma unroll
        for (int j = 0; j < 4; ++j) s_old[j] = sn[j];
        bf16_t* tmp = cur; cur = nxt; nxt = tmp;
    }
}

// ================= LayerNorm (in-place on d_out) =================
__global__ __launch_bounds__(256) void ln_kernel(
    float* __restrict__ io,
    const float* __restrict__ gamma,
    const float* __restrict__ beta)
{
    const size_t row = blockIdx.x;
    float* p = io + row * HID;
    const int tid = threadIdx.x;
    float4 v0 = *(const float4*)(p + tid * 4);
    float4 v1 = *(const float4*)(p + 1024 + tid * 4);
    float s  = v0.x + v0.y + v0.z + v0.w + v1.x + v1.y + v1.z + v1.w;
    float ss = v0.x * v0.x + v0.y * v0.y + v0.z * v0.z + v0.w * v0.w
             + v1.x * v1.x + v1.y * v1.y + v1.z * v1.z + v1.w * v1.w;
#pragma unroll
    for (int off = 32; off > 0; off >>= 1) {
        s  += __shfl_down(s, off, 64);
        ss += __shfl_down(ss, off, 64);
    }
    __shared__ float rs[4], rss[4];
    if ((tid & 63) == 0) { rs[tid >> 6] = s; rss[tid >> 6] = ss; }
    __syncthreads();
    s  = rs[0] + rs[1] + rs[2] + rs[3];
    ss = rss[0] + rss[1] + rss[2] + rss[3];
    const float mu = s * (1.f / HID);
    const float var = ss * (1.f / HID) - mu * mu;
    const float inv = rsqrtf(var + LN_EPS);
    const int c0 = tid * 4, c1 = 1024 + tid * 4;
    float4 g0 = *(const float4*)(gamma + c0);
    float4 g1 = *(const float4*)(gamma + c1);
    float4 b0 = *(const float4*)(beta + c0);
    float4 b1 = *(const float4*)(beta + c1);
    float4 o0, o1;
    o0.x = (v0.x - mu) * inv * g0.x + b0.x;
    o0.y = (v0.y - mu) * inv * g0.y + b0.y;
    o0.z = (v0.z - mu) * inv * g0.z + b0.z;
    o0.w = (v0.w - mu) * inv * g0.w + b0.w;
    o1.x = (v1.x - mu) * inv * g1.x + b1.x;
    o1.y = (v1.y - mu) * inv * g1.y + b1.y;
    o1.z = (v1.z - mu) * inv * g1.z + b1.z;
    o1.w = (v1.w - mu) * inv * g1.w + b1.w;
    *(float4*)(p + tid * 4) = o0;
    *(float4*)(p + 1024 + tid * 4) = o1;
}

extern "C" void kernel_launch(void* const* d_in, const int* in_sizes, int n_in,
                              void* d_out, int out_size, void* d_ws, size_t ws_size,
                              hipStream_t stream)
{
    const float* x     = (const float*)d_in[0];
    const float* Wi    = (const float*)d_in[1];
    const float* bias  = (const float*)d_in[2];
    const float* Wr    = (const float*)d_in[3];
    const float* mask  = (const float*)d_in[4];
    const float* tau   = (const float*)d_in[5];
    const float* gamma = (const float*)d_in[6];
    const float* beta  = (const float*)d_in[7];
    float* out = (float*)d_out;

    bf16_t* st0 = (bf16_t*)d_ws;
    bf16_t* st1 = st0 + (size_t)NBATCH * HID;
    int* flags  = (int*)(st1 + (size_t)NBATCH * HID);

    // 1) input projection -> d_out rows hold inp[b,t,:] (fp32); also zeroes flags
    gemm_proj<<<dim3(16, 64), 256, 0, stream>>>(x, Wi, bias, out, flags);
    // 2) persistent recurrence: overwrites d_out rows with pre-LN states
    recurrent<<<NBLK, RTHREADS, 0, stream>>>(Wr, mask, tau, out, st0, st1, flags);
    // 3) layernorm in-place
    ln_kernel<<<MTOT, 256, 0, stream>>>(out, gamma, beta);
}